// Round 6
// baseline (147.784 us; speedup 1.0000x reference)
//
#include <hip/hip_runtime.h>

// LSTM(units=64) over T=5, D_IN=1, then Dense(1, relu).  R6.
// fp16 MFMA for h@U (fp32 acc); gates via exp2 + merged rcp:
//   p=(1+ei)(1+eg), q=(1+ef):  c' = (c*p + q*(1-eg)) * rcp(p*q)
//   h = o*tanh(c') = (1-ec) * rcp((1+eo)(1+ec)),  ec = exp2(-2L*c')
// 5 exp2 + 2 rcp per cell; trans issue ~15 cyc/wave64 dominates
// (~105 of ~137 cyc/cell). R5 hit ~95% of the issue floor at ~80%
// wall utilization.
// R5 finding: residency pinned at ~3 blocks/CU across LDS 21-41KB and
// VGPR 52-68 -> the pin is the UNIFIED VGPR+AGPR file (CSV VGPR_Count
// excludes AGPRs holding Bf/acc; ~160 total/wave -> 3 waves/SIMD).
// R6: __launch_bounds__(256,4) caps total regs at 128/wave (hand count
// of true liveness ~115 -> should fit, no spill) AND HSTR 72->68 so
// LDS*4 blocks = 155KB <= 160KB. Goal: 4th resident wave fills the
// ~20% issue idle.
// Wave w owns gate-cols [w*16,w*16+16) of all 4 gates; Bf pinned via
// volatile asm (R1/R2 remat pathology). h via LDS f16 (stride 68:
// A-frag b128 reads stay at free 2-way bank conflicts). c in regs in
// C/D layout (col=lane&15, row=quad*4+reg).

typedef _Float16 f16x8 __attribute__((ext_vector_type(8)));
typedef float f32x4 __attribute__((ext_vector_type(4)));

#define MB 128       // rows per block (2 groups of 64)
#define NTHREADS 256
#define HSTR 68

__device__ __forceinline__ float ex2(float x) { return __builtin_amdgcn_exp2f(x); }
__device__ __forceinline__ float rcp(float x) { return __builtin_amdgcn_rcpf(x); }

__global__ __launch_bounds__(NTHREADS, 4) void lstm_fused(
    const float* __restrict__ x,   // [B,5,1]
    const float* __restrict__ W,   // [1,256]  gate order i,f,g,o
    const float* __restrict__ U,   // [64,256]
    const float* __restrict__ b,   // [256]
    const float* __restrict__ Wd,  // [64,1]
    const float* __restrict__ bd,  // [1]
    float* __restrict__ out,       // [B,1]
    int B)
{
    __shared__ _Float16 hbuf[2][2][64 * HSTR];  // [group][parity] 34.0 KB
    __shared__ float xs[5][MB];                 // 2.5 KB, [t][row]
    __shared__ float red[2][MB];                // 1 KB
    __shared__ float wds[64];                   // 0.25 KB

    const int tid  = threadIdx.x;
    const int wv   = tid >> 6;
    const int lane = tid & 63;
    const int l15  = lane & 15;
    const int quad = lane >> 4;
    const int row0 = blockIdx.x * MB;

    // stage x transposed to [t][row]; stage Wd
    for (int i = tid; i < MB * 5; i += NTHREADS)
        xs[i % 5][i / 5] = x[row0 * 5 + i];
    if (tid < 64) wds[tid] = Wd[tid];

    const float LOG2E = 1.44269504f;
    const float gscale[4] = {-LOG2E, -LOG2E, -2.0f * LOG2E, -LOG2E};
    const float CSC = -2.0f * LOG2E;

    // U B-fragments loaded ONCE (n = gate*64 + wv*16 + l15,
    // k = kh*32 + quad*8 + j), scaled, cvt f16, pinned vs remat.
    const int ncol = wv * 16 + l15;
    float Wf[4], bf[4];
    f16x8 Bf[4][2];
#pragma unroll
    for (int g = 0; g < 4; ++g) {
        const int n = g * 64 + ncol;
        const float s = gscale[g];
        Wf[g] = W[n] * s;
        bf[g] = b[n] * s;
#pragma unroll
        for (int kh = 0; kh < 2; ++kh) {
            f16x8 v;
#pragma unroll
            for (int j = 0; j < 8; ++j) {
                const int k = kh * 32 + quad * 8 + j;
                v[j] = (_Float16)(U[k * 256 + n] * s);
            }
            Bf[g][kh] = v;
            asm volatile("" : "+v"(Bf[g][kh]));
        }
    }

    float c[2][4][4];
#pragma unroll
    for (int gr = 0; gr < 2; ++gr)
#pragma unroll
        for (int a = 0; a < 4; ++a)
#pragma unroll
            for (int r = 0; r < 4; ++r) c[gr][a][r] = 0.0f;

    __syncthreads();  // xs visible

    // ---- t = 0 (h=0, c=0): c = i*g, h = o*tanh(c) ----
#pragma unroll
    for (int gr = 0; gr < 2; ++gr) {
#pragma unroll
        for (int rt = 0; rt < 4; ++rt) {
            const f32x4 xv = *(const f32x4*)&xs[0][gr * 64 + rt * 16 + quad * 4];
#pragma unroll
            for (int r = 0; r < 4; ++r) {
                const int rloc = rt * 16 + quad * 4 + r;
                const float ei = ex2(__builtin_fmaf(xv[r], Wf[0], bf[0]));
                const float eg = ex2(__builtin_fmaf(xv[r], Wf[2], bf[2]));
                const float eo = ex2(__builtin_fmaf(xv[r], Wf[3], bf[3]));
                const float r1 = rcp((1.0f + ei) * (1.0f + eg));
                const float cn = (1.0f - eg) * r1;            // i*g
                c[gr][rt][r] = cn;
                const float ec = ex2(cn * CSC);
                const float r2 = rcp((1.0f + eo) * (1.0f + ec));
                hbuf[gr][0][rloc * HSTR + ncol] = (_Float16)((1.0f - ec) * r2);
            }
        }
    }

    // ---- t = 1..4 ----
#pragma unroll
    for (int t = 1; t < 5; ++t) {
        const int src = (t + 1) & 1;
        const int dst = t & 1;
        __syncthreads();
#pragma unroll
        for (int gr = 0; gr < 2; ++gr) {
#pragma unroll
            for (int rt = 0; rt < 4; ++rt) {
                const int arow = rt * 16 + l15;   // A layout: m = lane&15
                const f16x8 a0 = *(const f16x8*)&hbuf[gr][src][arow * HSTR + quad * 8];
                const f16x8 a1 = *(const f16x8*)&hbuf[gr][src][arow * HSTR + 32 + quad * 8];
                const f32x4 xv = *(const f32x4*)&xs[t][gr * 64 + rt * 16 + quad * 4];
                f32x4 acc[4];
#pragma unroll
                for (int g = 0; g < 4; ++g) {
                    f32x4 z;
#pragma unroll
                    for (int r = 0; r < 4; ++r)
                        z[r] = __builtin_fmaf(xv[r], Wf[g], bf[g]);
                    z = __builtin_amdgcn_mfma_f32_16x16x32_f16(a0, Bf[g][0], z, 0, 0, 0);
                    z = __builtin_amdgcn_mfma_f32_16x16x32_f16(a1, Bf[g][1], z, 0, 0, 0);
                    acc[g] = z;
                }
#pragma unroll
                for (int r = 0; r < 4; ++r) {
                    const int rloc = rt * 16 + quad * 4 + r;
                    const float ei = ex2(acc[0][r]);
                    const float ef = ex2(acc[1][r]);
                    const float eg = ex2(acc[2][r]);
                    const float eo = ex2(acc[3][r]);
                    const float p  = (1.0f + ei) * (1.0f + eg);
                    const float q  = 1.0f + ef;
                    const float num = __builtin_fmaf(c[gr][rt][r], p, q * (1.0f - eg));
                    const float cn  = num * rcp(p * q);
                    c[gr][rt][r] = cn;
                    const float ec = ex2(cn * CSC);
                    const float r2 = rcp((1.0f + eo) * (1.0f + ec));
                    hbuf[gr][dst][rloc * HSTR + ncol] = (_Float16)((1.0f - ec) * r2);
                }
            }
        }
    }

    __syncthreads();  // h(t=4) complete in hbuf[*][0]

    // Dense(1, relu): each thread sums 32 of the 64 units for one row.
    {
        const int row = tid & 127;          // 0..127
        const int qh  = tid >> 7;           // 0..1
        const int gr  = row >> 6;
        const int rl  = row & 63;
        float s = 0.0f;
#pragma unroll
        for (int j = 0; j < 32; ++j)
            s += (float)hbuf[gr][0][rl * HSTR + qh * 32 + j] * wds[qh * 32 + j];
        red[qh][row] = s;
    }
    __syncthreads();
    if (tid < MB) {
        const float r = red[0][tid] + red[1][tid] + bd[0];
        out[row0 + tid] = fmaxf(r, 0.0f);
    }
}

extern "C" void kernel_launch(void* const* d_in, const int* in_sizes, int n_in,
                              void* d_out, int out_size, void* d_ws, size_t ws_size,
                              hipStream_t stream) {
    const float* x  = (const float*)d_in[0];
    const float* W  = (const float*)d_in[1];
    const float* U  = (const float*)d_in[2];
    const float* b  = (const float*)d_in[3];
    const float* Wd = (const float*)d_in[4];
    const float* bd = (const float*)d_in[5];
    float* out = (float*)d_out;
    const int B = in_sizes[0] / 5;
    const int grid = B / MB;   // 262144/128 = 2048 blocks
    lstm_fused<<<grid, NTHREADS, 0, stream>>>(x, W, U, b, Wd, bd, out, B);
}